// Round 4
// baseline (1385.434 us; speedup 1.0000x reference)
//
#include <hip/hip_runtime.h>

// ============================================================
// ScaleEncoder: pool2 -> [LN -> SSM-scan -> resid]x4 (fwd & bwd) -> merge -> upsample
// B=16 T=4096 D=256 N=16 L=4 SCALE=2, Ts=2048
// xw (fp32 residual stream, [2][16][2048][256]) lives in d_out.
// ws: xn_bf(/SP overlay) | deltaT(/merged overlay) | y_bf | xnT | dwT|owT|mergeT
// Scan: 2 threads per (dir,b,d) chunk (8 N-states each, DPP pair-exchange),
// chunked 2-pass + mid prefix kernel. delta AND x loaded as short8 from
// [d][t] layouts.
// ============================================================

typedef __attribute__((ext_vector_type(8))) short short8;
typedef __attribute__((ext_vector_type(4))) float f32x4;

#define TS 2048
#define NSEQ_D 8192u   // 2*16*256
#define NCH 32
#define CLEN 64

#if __has_builtin(__builtin_amdgcn_exp2f)
#define EXP2F(x) __builtin_amdgcn_exp2f(x)
#else
#define EXP2F(x) exp2f(x)
#endif
#if __has_builtin(__builtin_amdgcn_logf)
#define LOG2F(x) __builtin_amdgcn_logf(x)
#else
#define LOG2F(x) log2f(x)
#endif
#define LOG2E 1.44269504088896f
#define LN2 0.69314718055995f

__device__ __forceinline__ unsigned short f2bf(float f) {
  unsigned u = __float_as_uint(f);
  u = u + 0x7FFFu + ((u >> 16) & 1u);
  return (unsigned short)(u >> 16);
}
__device__ __forceinline__ float bf2f(unsigned short h) {
  return __uint_as_float(((unsigned)h) << 16);
}
__device__ __forceinline__ float softplus_fast(float x) {
  float e = EXP2F(-fabsf(x) * LOG2E);
  return fmaxf(x, 0.f) + LN2 * LOG2F(1.f + e);
}

// ---------------- weight transpose+bf16
__global__ __launch_bounds__(256) void wconv_kernel(
    const float* __restrict__ fdw, const float* __restrict__ bdw,
    const float* __restrict__ fow, const float* __restrict__ bow,
    const float* __restrict__ mw,
    unsigned short* __restrict__ dwT, unsigned short* __restrict__ owT,
    unsigned short* __restrict__ mT) {
  unsigned idx = blockIdx.x * 256u + threadIdx.x;   // < 1,179,648
  if (idx < 524288u) {
    unsigned dir = idx >> 18, l = (idx >> 16) & 3u, n = (idx >> 8) & 255u, k = idx & 255u;
    const float* s = dir ? bdw : fdw;
    dwT[idx] = f2bf(s[((l << 8) + k) * 256u + n]);
  } else if (idx < 1048576u) {
    unsigned r = idx - 524288u;
    unsigned dir = r >> 18, l = (r >> 16) & 3u, n = (r >> 8) & 255u, k = r & 255u;
    const float* s = dir ? bow : fow;
    owT[r] = f2bf(s[((l << 8) + k) * 256u + n]);
  } else {
    unsigned r = idx - 1048576u;                    // < 131072
    unsigned n = r >> 9, k = r & 511u;
    mT[r] = f2bf(mw[(k << 8) + n]);
  }
}

// ---------------- fused pool + LN (layer 0): x -> xw(both dirs), xn, xnT
__global__ __launch_bounds__(256) void ln0_kernel(
    const float* __restrict__ x, float* __restrict__ xw,
    unsigned short* __restrict__ xn, unsigned short* __restrict__ xnT,
    const float* __restrict__ fnw, const float* __restrict__ fnb,
    const float* __restrict__ bnw, const float* __restrict__ bnb) {
  __shared__ unsigned short ts0[32][256];
  __shared__ unsigned short ts1[32][256];
  const int tid = threadIdx.x;
  const int r = tid >> 3, cg = tid & 7;
  const unsigned row0 = blockIdx.x << 5;          // 0..32767 = b*2048 + j0
  const unsigned b = row0 >> 11, j0 = row0 & 2047u;
  const unsigned jj = j0 + (unsigned)r;
  const float* s0 = &x[(((b << 12) + (jj << 1)) << 8) + (unsigned)(cg << 5)];

  float v[32];
  float s = 0.f, q = 0.f;
#pragma unroll
  for (int i = 0; i < 8; ++i) {
    float4 f0 = ((const float4*)s0)[i];
    float4 f1 = ((const float4*)(s0 + 256))[i];
    float4 p;
    p.x = 0.5f * (f0.x + f1.x); p.y = 0.5f * (f0.y + f1.y);
    p.z = 0.5f * (f0.z + f1.z); p.w = 0.5f * (f0.w + f1.w);
    v[i * 4 + 0] = p.x; v[i * 4 + 1] = p.y; v[i * 4 + 2] = p.z; v[i * 4 + 3] = p.w;
    s += p.x + p.y + p.z + p.w;
    q += p.x * p.x + p.y * p.y + p.z * p.z + p.w * p.w;
  }
#pragma unroll
  for (int o = 4; o > 0; o >>= 1) { s += __shfl_xor(s, o); q += __shfl_xor(q, o); }
  float m = s * (1.f / 256.f);
  float rstd = rsqrtf(q * (1.f / 256.f) - m * m + 1e-5f);

  // write xw both dirs (pooled, pre-norm)
  float* w0 = &xw[((b << 11) + jj) * 256u + (unsigned)(cg << 5)];
  float* w1 = &xw[(((16u + b) << 11) + (2047u - jj)) * 256u + (unsigned)(cg << 5)];
#pragma unroll
  for (int i = 0; i < 8; ++i) {
    float4 p;
    p.x = v[i * 4 + 0]; p.y = v[i * 4 + 1]; p.z = v[i * 4 + 2]; p.w = v[i * 4 + 3];
    ((float4*)w0)[i] = p; ((float4*)w1)[i] = p;
  }

  const float* gf = fnw;  const float* bf_ = fnb;
  const float* gb = bnw;  const float* bb_ = bnb;
  unsigned xr0 = ((b << 11) + jj) * 256u + (unsigned)(cg << 5);
  unsigned xr1 = (((16u + b) << 11) + (2047u - jj)) * 256u + (unsigned)(cg << 5);
#pragma unroll
  for (int j = 0; j < 4; ++j) {
    short8 p0, p1;
#pragma unroll
    for (int e = 0; e < 8; ++e) {
      int i = j * 8 + e;
      int gi = (cg << 5) + i;
      float z = (v[i] - m) * rstd;
      unsigned short u0 = f2bf(z * gf[gi] + bf_[gi]);
      unsigned short u1 = f2bf(z * gb[gi] + bb_[gi]);
      p0[e] = (short)u0; p1[e] = (short)u1;
    }
    *(short8*)&xn[xr0 + (unsigned)(j << 3)] = p0;
    *(short8*)&xn[xr1 + (unsigned)(j << 3)] = p1;
    *(short8*)&ts0[r][(cg << 5) + (j << 3)] = p0;
    *(short8*)&ts1[r][(cg << 5) + (j << 3)] = p1;
  }
  __syncthreads();

  // transpose: thread owns d = tid
  {
    unsigned short u0[32], u1[32];
#pragma unroll
    for (int r2 = 0; r2 < 32; ++r2) { u0[r2] = ts0[r2][tid]; u1[r2] = ts1[r2][tid]; }
    unsigned seq0 = (b << 8) + (unsigned)tid;             // dir0: seqrow=b
    unsigned seq1 = 4096u + (b << 8) + (unsigned)tid;     // dir1
    unsigned base2 = 2016u - j0;                          // 2047-j0-31
#pragma unroll
    for (int j = 0; j < 4; ++j) {
      short8 pf, pr;
#pragma unroll
      for (int e = 0; e < 8; ++e) {
        pf[e] = (short)u0[j * 8 + e];
        pr[e] = (short)u1[31 - (j * 8 + e)];
      }
      *(short8*)&xnT[(seq0 << 11) + j0 + (unsigned)(j << 3)] = pf;
      *(short8*)&xnT[(seq1 << 11) + base2 + (unsigned)(j << 3)] = pr;
    }
  }
}

// ---------------- LayerNorm (layers 1..3): xw -> xn[t][d] + xnT[d][t]
__global__ __launch_bounds__(256) void ln_kernel(
    const float* __restrict__ xw, unsigned short* __restrict__ xn,
    unsigned short* __restrict__ xnT,
    const float* __restrict__ fnw, const float* __restrict__ fnb,
    const float* __restrict__ bnw, const float* __restrict__ bnb, int l) {
  __shared__ unsigned short ts[32][256];
  const int tid = threadIdx.x;
  const int r = tid >> 3, cg = tid & 7;
  const unsigned row0 = blockIdx.x << 5;          // 0..65535
  const unsigned dir = row0 >> 15;
  const float* g = (dir ? bnw : fnw) + (l << 8);
  const float* bb = (dir ? bnb : fnb) + (l << 8);
  const float* src = &xw[(row0 + (unsigned)r) * 256u + (unsigned)(cg << 5)];

  float v[32];
  float s = 0.f, q = 0.f;
#pragma unroll
  for (int i = 0; i < 8; ++i) {
    float4 p = ((const float4*)src)[i];
    v[i * 4 + 0] = p.x; v[i * 4 + 1] = p.y; v[i * 4 + 2] = p.z; v[i * 4 + 3] = p.w;
    s += p.x + p.y + p.z + p.w;
    q += p.x * p.x + p.y * p.y + p.z * p.z + p.w * p.w;
  }
#pragma unroll
  for (int o = 4; o > 0; o >>= 1) { s += __shfl_xor(s, o); q += __shfl_xor(q, o); }
  float m = s * (1.f / 256.f);
  float rstd = rsqrtf(q * (1.f / 256.f) - m * m + 1e-5f);

  unsigned xr = (row0 + (unsigned)r) * 256u + (unsigned)(cg << 5);
#pragma unroll
  for (int j = 0; j < 4; ++j) {
    short8 pk;
#pragma unroll
    for (int e = 0; e < 8; ++e) {
      int i = j * 8 + e;
      int gi = (cg << 5) + i;
      pk[e] = (short)f2bf((v[i] - m) * rstd * g[gi] + bb[gi]);
    }
    *(short8*)&xn[xr + (unsigned)(j << 3)] = pk;
    *(short8*)&ts[r][(cg << 5) + (j << 3)] = pk;
  }
  __syncthreads();

  {
    unsigned short u[32];
#pragma unroll
    for (int r2 = 0; r2 < 32; ++r2) u[r2] = ts[r2][tid];
    unsigned seq = ((row0 >> 11) << 8) + (unsigned)tid;   // dirb*256 + d
    unsigned t0 = row0 & 2047u;
#pragma unroll
    for (int j = 0; j < 4; ++j) {
      short8 pk;
#pragma unroll
      for (int e = 0; e < 8; ++e) pk[e] = (short)u[j * 8 + e];
      *(short8*)&xnT[(seq << 11) + t0 + (unsigned)(j << 3)] = pk;
    }
  }
}

// ---------------- layer GEMM: C[65536][256] = A @ W_dir + bias_dir
// MODE 0: deltaT[dirb,d,t] = softplus(C) bf16.  MODE 1: xw += C.
template <int MODE>
__global__ __launch_bounds__(256) void gemm_layer_k(
    const unsigned short* __restrict__ Abf, const unsigned short* __restrict__ WT,
    const float* __restrict__ bias_f, const float* __restrict__ bias_b, int l,
    unsigned short* __restrict__ delta_out, float* __restrict__ xw) {
  __shared__ __align__(16) unsigned short As[128 * 32];
  __shared__ __align__(16) unsigned short Bs[128 * 32];
  const int tid = threadIdx.x;
  const int lane = tid & 63, wave = tid >> 6;
  const int wm = wave >> 1, wn = wave & 1;
  const int lrow = lane & 15, lhi = lane >> 4;
  const int r0 = blockIdx.y << 7;
  const int c0 = blockIdx.x << 7;
  const int dir = r0 >> 15;
  const unsigned short* W = WT + (((dir << 2) + l) << 16);
  const float* bias = (dir ? bias_b : bias_f) + (l << 8);

  f32x4 acc[4][4] = {};

  for (int k0 = 0; k0 < 256; k0 += 32) {
    __syncthreads();
#pragma unroll
    for (int r = 0; r < 2; ++r) {
      int chunk = (r << 8) + tid;
      int row = chunk >> 2, qq = chunk & 3;
      *(int4*)&As[chunk << 3] =
          *(const int4*)&Abf[(unsigned)(r0 + row) * 256u + (unsigned)(k0 + (qq << 3))];
      *(int4*)&Bs[chunk << 3] =
          *(const int4*)&W[(unsigned)(c0 + row) * 256u + (unsigned)(k0 + (qq << 3))];
    }
    __syncthreads();
    short8 af[4], bfr[4];
#pragma unroll
    for (int m = 0; m < 4; ++m)
      af[m] = *(const short8*)&As[((wm << 6) + (m << 4) + lrow) * 32 + (lhi << 3)];
#pragma unroll
    for (int n = 0; n < 4; ++n)
      bfr[n] = *(const short8*)&Bs[((wn << 6) + (n << 4) + lrow) * 32 + (lhi << 3)];
#pragma unroll
    for (int m = 0; m < 4; ++m)
#pragma unroll
      for (int n = 0; n < 4; ++n)
        acc[m][n] = __builtin_amdgcn_mfma_f32_16x16x32_bf16(af[m], bfr[n], acc[m][n], 0, 0, 0);
  }

  const int seqrow = r0 >> 11;
  const int tloc = r0 & 2047;
#pragma unroll
  for (int m = 0; m < 4; ++m) {
#pragma unroll
    for (int n = 0; n < 4; ++n) {
      const int col = c0 + (wn << 6) + (n << 4) + lrow;
      const float bv = bias[col];
      if (MODE == 0) {
        ushort4 pk;
#pragma unroll
        for (int j = 0; j < 4; ++j) {
          float v = acc[m][n][j] + bv;
          ((unsigned short*)&pk)[j] = f2bf(softplus_fast(v));
        }
        const unsigned tb = (unsigned)(tloc + (wm << 6) + (m << 4) + (lhi << 2));
        *(ushort4*)&delta_out[(((unsigned)((seqrow << 8) + col)) << 11) + tb] = pk;
      } else {
#pragma unroll
        for (int j = 0; j < 4; ++j) {
          const unsigned grow = (unsigned)(r0 + (wm << 6) + (m << 4) + (lhi << 2) + j);
          xw[grow * 256u + (unsigned)col] += acc[m][n][j] + bv;
        }
      }
    }
  }
}

// ---------------- chunked SSM scan: 2 threads (h=0/1) per (seq, chunk) ----------------
// SP float layout per (seq, c): [S 0..15 | P 0..15]; h-half = 8 of each.
// After scan_mid, the S slots hold the INCOMING state sigma for each chunk.

__global__ __launch_bounds__(256, 8) void scan_pass1(
    const unsigned short* __restrict__ deltaT, const unsigned short* __restrict__ xnT,
    float4* __restrict__ SP,
    const float* __restrict__ alog_f, const float* __restrict__ alog_b, int l) {
  const unsigned gid = blockIdx.x * 256u + threadIdx.x;
  const unsigned h = gid & 1u;
  const unsigned seq = (gid >> 1) & (NSEQ_D - 1u);
  const unsigned c = gid >> 14;                       // 0..30
  const int d = seq & 255;
  const int dir = seq >> 12;
  const float* alog = (dir ? alog_b : alog_f) + (((l << 8) + d) << 4) + (h << 3);

  float c2[8];
#pragma unroll
  for (int qq = 0; qq < 2; ++qq) {
    float4 av = ((const float4*)alog)[qq];
    c2[qq * 4 + 0] = -(softplus_fast(av.x) + 1e-4f) * LOG2E;
    c2[qq * 4 + 1] = -(softplus_fast(av.y) + 1e-4f) * LOG2E;
    c2[qq * 4 + 2] = -(softplus_fast(av.z) + 1e-4f) * LOG2E;
    c2[qq * 4 + 3] = -(softplus_fast(av.w) + 1e-4f) * LOG2E;
  }

  const unsigned base = (seq << 11) + c * CLEN;
  float s[8];
#pragma unroll
  for (int n = 0; n < 8; ++n) s[n] = 0.f;
  float dsum = 0.f;

  for (int tt = 0; tt < CLEN; tt += 8) {
    short8 dv = *(const short8*)&deltaT[base + (unsigned)tt];
    short8 xv = *(const short8*)&xnT[base + (unsigned)tt];
#pragma unroll
    for (int k = 0; k < 8; ++k) {
      float dt = bf2f((unsigned short)dv[k]);
      float u = dt * bf2f((unsigned short)xv[k]);
      dsum += dt;
#pragma unroll
      for (int n = 0; n < 8; ++n)
        s[n] = fmaf(EXP2F(c2[n] * dt), s[n], u);
    }
  }

  float4* o = &SP[((seq * NCH + c) << 3) + (h << 1)];
  float4 v0, v1;
  v0.x = s[0]; v0.y = s[1]; v0.z = s[2]; v0.w = s[3];
  v1.x = s[4]; v1.y = s[5]; v1.z = s[6]; v1.w = s[7];
  o[0] = v0; o[1] = v1;
  float4 p0, p1;
  p0.x = EXP2F(c2[0] * dsum); p0.y = EXP2F(c2[1] * dsum);
  p0.z = EXP2F(c2[2] * dsum); p0.w = EXP2F(c2[3] * dsum);
  p1.x = EXP2F(c2[4] * dsum); p1.y = EXP2F(c2[5] * dsum);
  p1.z = EXP2F(c2[6] * dsum); p1.w = EXP2F(c2[7] * dsum);
  o[4] = p0; o[5] = p1;
}

// mid: per (seq,n) serial combine; S slots become incoming sigma per chunk.
__global__ __launch_bounds__(256) void scan_mid(float* __restrict__ SP) {
  const unsigned t = blockIdx.x * 256u + threadIdx.x;   // < 131072
  const unsigned seq = t >> 4;
  const unsigned n = t & 15u;
  float* base = SP + (size_t)seq * (NCH * 32) + n;
  float sg = 0.f;
#pragma unroll 4
  for (int c = 0; c < NCH; ++c) {
    float S = base[c * 32];
    float P = base[c * 32 + 16];
    base[c * 32] = sg;
    sg = fmaf(P, sg, S);
  }
}

__global__ __launch_bounds__(256, 8) void scan_pass2(
    const unsigned short* __restrict__ deltaT, const unsigned short* __restrict__ xnT,
    unsigned short* __restrict__ y, const float4* __restrict__ SP,
    const float* __restrict__ alog_f, const float* __restrict__ alog_b,
    const float* __restrict__ bp_f, const float* __restrict__ bp_b, int l) {
  const unsigned gid = blockIdx.x * 256u + threadIdx.x;
  const unsigned h = gid & 1u;
  const unsigned seq = (gid >> 1) & (NSEQ_D - 1u);
  const unsigned c = gid >> 14;                       // 0..31
  const int d = seq & 255;
  const unsigned seqrow = seq >> 8;
  const int dir = seq >> 12;
  const float* alog = (dir ? alog_b : alog_f) + (((l << 8) + d) << 4) + (h << 3);
  const float* bpp = (dir ? bp_b : bp_f) + (((l << 8) + d) << 4) + (h << 3);

  float c2[8], bp[8];
#pragma unroll
  for (int qq = 0; qq < 2; ++qq) {
    float4 av = ((const float4*)alog)[qq];
    c2[qq * 4 + 0] = -(softplus_fast(av.x) + 1e-4f) * LOG2E;
    c2[qq * 4 + 1] = -(softplus_fast(av.y) + 1e-4f) * LOG2E;
    c2[qq * 4 + 2] = -(softplus_fast(av.z) + 1e-4f) * LOG2E;
    c2[qq * 4 + 3] = -(softplus_fast(av.w) + 1e-4f) * LOG2E;
    float4 bv = ((const float4*)bpp)[qq];
    bp[qq * 4 + 0] = bv.x; bp[qq * 4 + 1] = bv.y;
    bp[qq * 4 + 2] = bv.z; bp[qq * 4 + 3] = bv.w;
  }

  // incoming state sigma (written by scan_mid into the S slots)
  float s[8];
  {
    const float4* sg = &SP[((seq * NCH + c) << 3) + (h << 1)];
    float4 v0 = sg[0], v1 = sg[1];
    s[0] = v0.x; s[1] = v0.y; s[2] = v0.z; s[3] = v0.w;
    s[4] = v1.x; s[5] = v1.y; s[6] = v1.z; s[7] = v1.w;
  }

  const unsigned t0 = c * CLEN;
  const unsigned base = (seq << 11) + t0;
  const unsigned ybase = (seqrow << 19) + (t0 << 8) + (unsigned)d;

  for (int tt = 0; tt < CLEN; tt += 8) {
    short8 dv = *(const short8*)&deltaT[base + (unsigned)tt];
    short8 xv = *(const short8*)&xnT[base + (unsigned)tt];
#pragma unroll
    for (int k = 0; k < 8; ++k) {
      float dt = bf2f((unsigned short)dv[k]);
      float u = dt * bf2f((unsigned short)xv[k]);
#pragma unroll
      for (int n = 0; n < 8; ++n)
        s[n] = fmaf(EXP2F(c2[n] * dt), s[n], u);
      float ya = bp[0] * s[0], yb = bp[1] * s[1];
      ya = fmaf(bp[2], s[2], ya); yb = fmaf(bp[3], s[3], yb);
      ya = fmaf(bp[4], s[4], ya); yb = fmaf(bp[5], s[5], yb);
      ya = fmaf(bp[6], s[6], ya); yb = fmaf(bp[7], s[7], yb);
      float ys = ya + yb;
      int pr = __builtin_amdgcn_update_dpp(0, __float_as_int(ys), 0xB1, 0xf, 0xf, 1);
      ys += __int_as_float(pr);
      if (h == 0) y[ybase + (unsigned)((tt + k) << 8)] = f2bf(ys);
    }
  }
}

// ---------------- merge GEMM: A gathered from xw (fp32->bf16 in stage) @ mergeT
__global__ __launch_bounds__(256) void gemm_merge_k(
    const float* __restrict__ xw, const unsigned short* __restrict__ MT,
    const float* __restrict__ mb, float* __restrict__ merged) {
  __shared__ __align__(16) unsigned short As[128 * 32];
  __shared__ __align__(16) unsigned short Bs[128 * 32];
  const int tid = threadIdx.x;
  const int lane = tid & 63, wave = tid >> 6;
  const int wm = wave >> 1, wn = wave & 1;
  const int lrow = lane & 15, lhi = lane >> 4;
  const int r0 = blockIdx.y << 7;
  const int c0 = blockIdx.x << 7;

  f32x4 acc[4][4] = {};

  for (int k0 = 0; k0 < 512; k0 += 32) {
    __syncthreads();
    {
      int row = tid >> 1;
      int cgo = (tid & 1) << 4;
      int gr = r0 + row;
      int b = gr >> 11, t = gr & 2047;
      unsigned srow = (k0 < 256) ? (unsigned)(b * 2048 + t)
                                 : (unsigned)((16 + b) * 2048 + (2047 - t));
      unsigned kk = (unsigned)((k0 & 255) + cgo);
      const float4* ap = (const float4*)&xw[srow * 256u + kk];
      float4 f0 = ap[0], f1 = ap[1], f2v = ap[2], f3 = ap[3];
      short8 p0, p1;
      p0[0] = (short)f2bf(f0.x); p0[1] = (short)f2bf(f0.y);
      p0[2] = (short)f2bf(f0.z); p0[3] = (short)f2bf(f0.w);
      p0[4] = (short)f2bf(f1.x); p0[5] = (short)f2bf(f1.y);
      p0[6] = (short)f2bf(f1.z); p0[7] = (short)f2bf(f1.w);
      p1[0] = (short)f2bf(f2v.x); p1[1] = (short)f2bf(f2v.y);
      p1[2] = (short)f2bf(f2v.z); p1[3] = (short)f2bf(f2v.w);
      p1[4] = (short)f2bf(f3.x); p1[5] = (short)f2bf(f3.y);
      p1[6] = (short)f2bf(f3.z); p1[7] = (short)f2bf(f3.w);
      *(short8*)&As[row * 32 + cgo] = p0;
      *(short8*)&As[row * 32 + cgo + 8] = p1;
      const int4* bp4 = (const int4*)&MT[(unsigned)(c0 + row) * 512u + (unsigned)(k0 + cgo)];
      *(int4*)&Bs[row * 32 + cgo] = bp4[0];
      *(int4*)&Bs[row * 32 + cgo + 8] = bp4[1];
    }
    __syncthreads();
    short8 af[4], bfr[4];
#pragma unroll
    for (int m = 0; m < 4; ++m)
      af[m] = *(const short8*)&As[((wm << 6) + (m << 4) + lrow) * 32 + (lhi << 3)];
#pragma unroll
    for (int n = 0; n < 4; ++n)
      bfr[n] = *(const short8*)&Bs[((wn << 6) + (n << 4) + lrow) * 32 + (lhi << 3)];
#pragma unroll
    for (int m = 0; m < 4; ++m)
#pragma unroll
      for (int n = 0; n < 4; ++n)
        acc[m][n] = __builtin_amdgcn_mfma_f32_16x16x32_bf16(af[m], bfr[n], acc[m][n], 0, 0, 0);
  }

#pragma unroll
  for (int m = 0; m < 4; ++m) {
#pragma unroll
    for (int n = 0; n < 4; ++n) {
      const int col = c0 + (wn << 6) + (n << 4) + lrow;
      const float bv = mb[col];
#pragma unroll
      for (int j = 0; j < 4; ++j) {
        const unsigned grow = (unsigned)(r0 + (wm << 6) + (m << 4) + (lhi << 2) + j);
        merged[grow * 256u + (unsigned)col] = acc[m][n][j] + bv;
      }
    }
  }
}

// ---------------- linear upsample x2 (align_corners=False)
__global__ __launch_bounds__(256) void up_kernel(const float4* __restrict__ m4,
                                                 float4* __restrict__ out4) {
  unsigned idx = blockIdx.x * 256u + threadIdx.x;   // < 4,194,304
  unsigned d4 = idx & 63u;
  unsigned t = (idx >> 6) & 4095u;
  unsigned b = idx >> 18;
  unsigned j = t >> 1;
  unsigned lo, hi; float wlo, whi;
  if (t & 1u) { lo = j; hi = (j < 2047u) ? j + 1u : 2047u; wlo = 0.75f; whi = 0.25f; }
  else { lo = j ? j - 1u : 0u; hi = j; wlo = 0.25f; whi = 0.75f; }
  float4 a = m4[((b << 11) + lo) * 64u + d4];
  float4 c = m4[((b << 11) + hi) * 64u + d4];
  float4 o;
  o.x = wlo * a.x + whi * c.x; o.y = wlo * a.y + whi * c.y;
  o.z = wlo * a.z + whi * c.z; o.w = wlo * a.w + whi * c.w;
  out4[((b << 12) + t) * 64u + d4] = o;
}

// ============================================================
extern "C" void kernel_launch(void* const* d_in, const int* in_sizes, int n_in,
                              void* d_out, int out_size, void* d_ws, size_t ws_size,
                              hipStream_t stream) {
  const float* x    = (const float*)d_in[0];
  const float* fnw  = (const float*)d_in[1];
  const float* fnb  = (const float*)d_in[2];
  const float* fdw  = (const float*)d_in[3];
  const float* fdb  = (const float*)d_in[4];
  const float* falog = (const float*)d_in[5];
  const float* fbp  = (const float*)d_in[6];
  const float* fow  = (const float*)d_in[7];
  const float* fob  = (const float*)d_in[8];
  const float* bnw  = (const float*)d_in[9];
  const float* bnb  = (const float*)d_in[10];
  const float* bdw  = (const float*)d_in[11];
  const float* bdb  = (const float*)d_in[12];
  const float* balog = (const float*)d_in[13];
  const float* bbp  = (const float*)d_in[14];
  const float* bow  = (const float*)d_in[15];
  const float* bob  = (const float*)d_in[16];
  const float* mw   = (const float*)d_in[17];
  const float* mb   = (const float*)d_in[18];

  char* ws = (char*)d_ws;
  const size_t SZ = 33554432;
  unsigned short* xn_bf  = (unsigned short*)(ws);            // [t][d]; SP overlays
  unsigned short* deltaT = (unsigned short*)(ws + SZ);       // [d][t]; merged overlays
  unsigned short* y_bf   = (unsigned short*)(ws + 2 * SZ);   // [t][d]
  unsigned short* xnT    = (unsigned short*)(ws + 3 * SZ);   // [d][t]
  unsigned short* dwT    = (unsigned short*)(ws + 4 * SZ);
  unsigned short* owT    = dwT + 524288;
  unsigned short* mergeT = owT + 524288;
  float4* SP             = (float4*)xn_bf;   // 8192*32*128B = SZ exactly; xn dead by pass1
  float* merged          = (float*)deltaT;   // dead by merge time
  float* xw              = (float*)d_out;    // [2][16][2048][256] fp32 residual stream

  wconv_kernel<<<4608, 256, 0, stream>>>(fdw, bdw, fow, bow, mw, dwT, owT, mergeT);
  ln0_kernel<<<1024, 256, 0, stream>>>(x, xw, xn_bf, xnT, fnw, fnb, bnw, bnb);

  for (int l = 0; l < 4; ++l) {
    if (l > 0)
      ln_kernel<<<2048, 256, 0, stream>>>(xw, xn_bf, xnT, fnw, fnb, bnw, bnb, l);
    gemm_layer_k<0><<<dim3(2, 512), 256, 0, stream>>>(xn_bf, dwT, fdb, bdb, l, deltaT, nullptr);
    scan_pass1<<<64 * (NCH - 1), 256, 0, stream>>>(deltaT, xnT, SP, falog, balog, l);
    scan_mid<<<512, 256, 0, stream>>>((float*)SP);
    scan_pass2<<<64 * NCH, 256, 0, stream>>>(deltaT, xnT, y_bf, SP, falog, balog, fbp, bbp, l);
    gemm_layer_k<1><<<dim3(2, 512), 256, 0, stream>>>(y_bf, owT, fob, bob, l, nullptr, xw);
  }

  gemm_merge_k<<<dim3(2, 256), 256, 0, stream>>>(xw, mergeT, mb, merged);
  up_kernel<<<16384, 256, 0, stream>>>((const float4*)merged, (float4*)d_out);
}